// Round 6
// baseline (223.818 us; speedup 1.0000x reference)
//
#include <hip/hip_runtime.h>
#include <stdint.h>

// Problem shape (fixed by setup_inputs)
#define BB 64
#define CC 128
#define HW 3136
#define NPR (CC * HW)        // 401408 elements per batch row
#define NBINS 8192
#define BIN_SHIFT 19         // key >> 19 -> top 13 bits (sign + 8 exp + 4 mantissa)
#define KEY_LOW 0x7FFFFu     // low 19 key bits (all candidates share the top 13)
#define GROUPS 32            // blocks per row
#define GCH 4                // channels per block
#define NF4 3136             // GCH*HW/4 float4 per block = 12*256 + 64
#define F4CH 784             // HW/4 float4 per channel

typedef float vf4 __attribute__((ext_vector_type(4)));  // native vector for nontemporal

// Workspace layout (bytes):
//   [512, 1536)     : rowmeta int2[64]  {binstar, E}
//   [2048, 2304)    : counters u32[64]
//   [4096, 4096+2MB): hist u32[64][8192]
//   [CAND_OFF, ...) : candidates u64[64][cap]  (packed (key&0x7FFFF)<<32 | ~idx)
#define ROWMETA_OFF 512
#define COUNTER_OFF 2048
#define HIST_OFF 4096
#define CAND_OFF (HIST_OFF + (size_t)BB * NBINS * 4)

__device__ __forceinline__ uint32_t tokey(float b) {
    uint32_t u = __float_as_uint(b);
    return u ^ (uint32_t)(((int32_t)u >> 31) | 0x80000000);
}

__device__ __forceinline__ float boostf(const float* dc, int c, int K) {
    float td = (float)((double)K / (double)NPR);   // jnp.float32(k/n)
    float d = td - dc[c];
    return (float)exp((double)d);
}

// ---------------- kernel 1: per-row histogram ----------------
// MLP product = waves/CU x loads-in-flight/wave (r5 lesson: need BOTH).
// u16-packed hist (16 KiB LDS, carry-free: 4*3136 < 65536, proven r2) +
// 2048 blocks -> 7-8 blocks/CU; all 13 loads issued up front (52 data VGPRs,
// no launch-bounds cap per r3 lesson).
__global__ __launch_bounds__(256) void k_hist(const float* __restrict__ x,
                                              const float* __restrict__ dc,
                                              const int* __restrict__ kptr,
                                              uint32_t* __restrict__ hist) {
    __shared__ uint32_t lh32[NBINS / 2];           // 16 KiB, bin b in half (b&1) of [b>>1]
    __shared__ float sbf[GCH];
    const int tid = threadIdx.x;
    for (int i = tid; i < NBINS / 2; i += 256) lh32[i] = 0;
    if (tid < GCH) {
        int c0 = (blockIdx.x & (GROUPS - 1)) * GCH;
        sbf[tid] = boostf(dc, c0 + tid, *kptr);
    }
    __syncthreads();

    const int row = blockIdx.x >> 5;
    const int c0 = (blockIdx.x & (GROUPS - 1)) * GCH;
    const float4* xp = (const float4*)(x + (size_t)row * NPR + (size_t)c0 * HW);

#define HPROC(av, tv)                                                          \
    do {                                                                       \
        float f_ = sbf[(tv) / F4CH];                                           \
        uint32_t b_;                                                           \
        b_ = tokey((av).x * f_) >> BIN_SHIFT;                                  \
        atomicAdd(&lh32[b_ >> 1], 1u << ((b_ & 1) << 4));                      \
        b_ = tokey((av).y * f_) >> BIN_SHIFT;                                  \
        atomicAdd(&lh32[b_ >> 1], 1u << ((b_ & 1) << 4));                      \
        b_ = tokey((av).z * f_) >> BIN_SHIFT;                                  \
        atomicAdd(&lh32[b_ >> 1], 1u << ((b_ & 1) << 4));                      \
        b_ = tokey((av).w * f_) >> BIN_SHIFT;                                  \
        atomicAdd(&lh32[b_ >> 1], 1u << ((b_ & 1) << 4));                      \
    } while (0)

    // Issue all loads first (13 in flight incl. tail), then process in order.
    float4 v[12];
    #pragma unroll
    for (int g = 0; g < 12; ++g) v[g] = xp[tid + 256 * g];
    float4 tl;
    if (tid < 64) tl = xp[3072 + tid];
    #pragma unroll
    for (int g = 0; g < 12; ++g) HPROC(v[g], tid + 256 * g);
    if (tid < 64) HPROC(tl, 3072 + tid);
#undef HPROC

    __syncthreads();
    uint32_t* gh = hist + (size_t)row * NBINS;
    for (int i = tid; i < NBINS / 2; i += 256) {   // sparse unpacked flush (~hot bins only)
        uint32_t w = lh32[i];
        if (w & 0xFFFFu) atomicAdd(&gh[2 * i], w & 0xFFFFu);
        if (w >> 16)     atomicAdd(&gh[2 * i + 1], w >> 16);
    }
}

// ------- kernel 2: inline boundary scan + write pass + candidate compaction --
// Each block recomputes its row's boundary bin from hist (L2/L3-hot, 32 KB);
// hist values held in 32 unrolled VGPRs (retire before main loop). Designated
// block publishes rowmeta for k_select. Main loop: all 13 loads up front.
__global__ __launch_bounds__(256) void k_write_scan(const float* __restrict__ x,
                                                    const float* __restrict__ dc,
                                                    const int* __restrict__ kptr,
                                                    const uint32_t* __restrict__ hist,
                                                    int2* __restrict__ rowmeta,
                                                    float* __restrict__ out,
                                                    unsigned long long* __restrict__ cand,
                                                    uint32_t* __restrict__ counters,
                                                    int cap) {
    const int tid = threadIdx.x;
    const int row = blockIdx.x >> 5;               // 64 rows x 32 groups of 4 channels
    const int c0 = (blockIdx.x & (GROUPS - 1)) * GCH;
    const int K = *kptr;

    __shared__ float sbf[GCH];
    __shared__ uint32_t lcnt, gbase;
    __shared__ unsigned long long lbuf[2048];      // 16 KiB
    __shared__ uint32_t csum[256];
    __shared__ int2 smeta;
    if (tid == 0) lcnt = 0;
    if (tid < GCH) sbf[tid] = boostf(dc, c0 + tid, K);

    // ---- inline per-block boundary scan ----
    {
        const uint32_t* gh = hist + (size_t)row * NBINS;
        uint32_t Ku = (uint32_t)K;
        int hi = NBINS - 1 - 32 * tid;             // chunk covers [hi-31, hi], descending
        uint32_t hv[32];                           // regs, static indexing only
        #pragma unroll
        for (int j = 0; j < 32; j++) hv[j] = gh[hi - j];
        uint32_t ssum = 0;
        #pragma unroll
        for (int j = 0; j < 32; j++) ssum += hv[j];
        csum[tid] = ssum;
        __syncthreads();
        for (int off = 1; off < 256; off <<= 1) {  // inclusive scan, descending-bin order
            uint32_t v = (tid >= off) ? csum[tid - off] : 0u;
            __syncthreads();
            csum[tid] += v;
            __syncthreads();
        }
        uint32_t incl = csum[tid];
        uint32_t excl = incl - ssum;
        if (excl < Ku && incl >= Ku) {             // exactly one thread
            uint32_t cum = excl;
            #pragma unroll
            for (int j = 0; j < 32; j++) {
                if (cum + hv[j] >= Ku) { smeta = make_int2(hi - j, (int)(Ku - cum)); break; }
                cum += hv[j];
            }
        }
        __syncthreads();
    }
    const int bstar = smeta.x;
    if (tid == 0 && (blockIdx.x & (GROUPS - 1)) == 0) rowmeta[row] = smeta;

    size_t base = (size_t)row * NPR + (size_t)c0 * HW;
    const float4* xp = (const float4*)(x + base);  // mostly L3-resident after pass 1
    vf4* op = (vf4*)(out + base);
    int jbase = c0 * HW;

// one float4 -> thresholded out-store + boundary-bin candidate capture
#define PROC4(av, tu)                                                            \
    do {                                                                         \
        float fv = sbf[(tu) / F4CH];                                             \
        vf4 oa;                                                                  \
        float* ai = (float*)&(av);                                               \
        _Pragma("unroll")                                                        \
        for (int q = 0; q < 4; q++) {                                            \
            float xv = ai[q];                                                    \
            uint32_t key = tokey(xv * fv);                                       \
            int bin = (int)(key >> BIN_SHIFT);                                   \
            oa[q] = (bin > bstar) ? xv : 0.0f;                                   \
            if (bin == bstar) {                                                  \
                uint32_t j = (uint32_t)(jbase + 4 * (tu) + q);                   \
                unsigned long long packed =                                      \
                    ((unsigned long long)(key & KEY_LOW) << 32) | (uint32_t)(~j);\
                uint32_t pos = atomicAdd(&lcnt, 1u);                             \
                if (pos < 2048u) lbuf[pos] = packed;                             \
                else {                                                           \
                    uint32_t gp = atomicAdd(&counters[row], 1u);                 \
                    if ((int)gp < cap) cand[(size_t)row * cap + gp] = packed;    \
                }                                                                \
            }                                                                    \
        }                                                                        \
        __builtin_nontemporal_store(oa, &op[(tu)]);                              \
    } while (0)

    // Issue all loads first (13 in flight incl. tail), then process in order.
    float4 v[12];
    #pragma unroll
    for (int g = 0; g < 12; ++g) v[g] = xp[tid + 256 * g];
    float4 tl;
    if (tid < 64) tl = xp[3072 + tid];
    #pragma unroll
    for (int g = 0; g < 12; ++g) PROC4(v[g], tid + 256 * g);
    if (tid < 64) PROC4(tl, 3072 + tid);
#undef PROC4

    __syncthreads();
    uint32_t m = lcnt < 2048u ? lcnt : 2048u;
    if (tid == 0) gbase = atomicAdd(&counters[row], m);
    __syncthreads();
    for (uint32_t i = tid; i < m; i += 256) {
        uint32_t pos = gbase + i;
        if ((int)pos < cap) cand[(size_t)row * cap + pos] = lbuf[i];
    }
}

// ---------------- kernel 3: exact radix-select among candidates + scatter ----
__global__ __launch_bounds__(1024) void k_select(const float* __restrict__ x,
                                                 float* __restrict__ out,
                                                 const unsigned long long* __restrict__ cand,
                                                 const uint32_t* __restrict__ counters,
                                                 const int2* __restrict__ rowmeta,
                                                 int cap) {
    int row = blockIdx.x;
    uint32_t cnt = counters[row];
    if ((int)cnt > cap) cnt = (uint32_t)cap;
    int E = rowmeta[row].y;
    const unsigned long long* cp = cand + (size_t)row * cap;
    int tid = threadIdx.x;

    __shared__ uint32_t hist[256];
    __shared__ uint32_t sufs[256];
    __shared__ unsigned long long buf[6144];       // 48 KiB survivor compaction
    __shared__ uint32_t scnt;
    __shared__ int sh_d, sh_done;

    unsigned long long prefix = 0ull, mask = 0ull, thr = 0ull;
    uint32_t remaining = (uint32_t)E;
    bool compacted = false;
    uint32_t csize = cnt;
    if (tid == 0) sh_done = 0;

    for (int shift = 48; shift >= 0; shift -= 8) {
        if (tid < 256) hist[tid] = 0;
        __syncthreads();
        if (!compacted) {
            for (uint32_t s = tid; s < cnt; s += 1024) {
                unsigned long long v = cp[s];
                if ((v & mask) == prefix)
                    atomicAdd(&hist[(uint32_t)(v >> shift) & 255u], 1u);
            }
        } else {
            for (uint32_t s = tid; s < csize; s += 1024)
                atomicAdd(&hist[(uint32_t)(buf[s] >> shift) & 255u], 1u);
        }
        __syncthreads();
        if (tid < 256) sufs[tid] = hist[tid];
        __syncthreads();
        for (int off = 1; off < 256; off <<= 1) {  // suffix sums (descending scan)
            uint32_t add = 0;
            if (tid < 256 && tid + off < 256) add = sufs[tid + off];
            __syncthreads();
            if (tid < 256) sufs[tid] += add;
            __syncthreads();
        }
        if (tid < 256) {
            uint32_t sd = sufs[tid];
            uint32_t sn = (tid < 255) ? sufs[tid + 1] : 0u;
            if (sd >= remaining && sn < remaining) sh_d = tid;
        }
        __syncthreads();
        int d = sh_d;
        uint32_t cumG = (d < 255) ? sufs[d + 1] : 0u;
        uint32_t binC = sufs[d] - cumG;
        unsigned long long npref = prefix | ((unsigned long long)(uint32_t)d << shift);
        unsigned long long nmask = mask | (0xFFull << shift);
        bool done = (sufs[d] == remaining);        // whole bin completes exactly
        if (done) {
            thr = npref;
            if (tid == 0) sh_done = 1;
        }
        remaining -= cumG;
        __syncthreads();                           // sufs reads done; sh_done visible
        if (!sh_done && binC <= 6144u && shift > 0) {
            if (tid == 0) scnt = 0;
            __syncthreads();
            // Survivors are exactly {v : (v & nmask)==npref}: refilter from global
            // (register-lean; proven r1-r5).
            for (uint32_t s = tid; s < cnt; s += 1024) {
                unsigned long long v = cp[s];
                if ((v & nmask) == npref) {
                    uint32_t p = atomicAdd(&scnt, 1u);
                    buf[p] = v;
                }
            }
            __syncthreads();
            csize = binC;
            compacted = true;
        }
        prefix = npref;
        mask = nmask;
        if (sh_done) break;
    }
    if (!sh_done) thr = prefix;                    // fully resolved (all v distinct)

    const float* xr = x + (size_t)row * NPR;
    float* orow = out + (size_t)row * NPR;
    for (uint32_t s = tid; s < cnt; s += 1024) {
        unsigned long long v = cp[s];
        if (v >= thr) {
            uint32_t j = ~(uint32_t)v;
            orow[j] = xr[j];
        }
    }
}

extern "C" void kernel_launch(void* const* d_in, const int* in_sizes, int n_in,
                              void* d_out, int out_size, void* d_ws, size_t ws_size,
                              hipStream_t stream) {
    const float* x  = (const float*)d_in[0];
    const float* dc = (const float*)d_in[1];
    const int* kptr = (const int*)d_in[2];
    float* out = (float*)d_out;

    char* ws = (char*)d_ws;
    int2* rowmeta       = (int2*)(ws + ROWMETA_OFF);
    uint32_t* counters  = (uint32_t*)(ws + COUNTER_OFF);
    uint32_t* hist      = (uint32_t*)(ws + HIST_OFF);
    unsigned long long* cand = (unsigned long long*)(ws + CAND_OFF);

    size_t cap_sz = (ws_size > CAND_OFF) ? (ws_size - CAND_OFF) / ((size_t)BB * 8) : 0;
    if (cap_sz > 65536) cap_sz = 65536;
    int cap = (int)cap_sz;

    (void)hipMemsetAsync(ws, 0, CAND_OFF, stream); // zero meta + counters + hist
    k_hist<<<BB * GROUPS, 256, 0, stream>>>(x, dc, kptr, hist);
    k_write_scan<<<BB * GROUPS, 256, 0, stream>>>(x, dc, kptr, hist, rowmeta, out,
                                                  cand, counters, cap);
    k_select<<<BB, 1024, 0, stream>>>(x, out, cand, counters, rowmeta, cap);
}